// Round 20
// baseline (82.029 us; speedup 1.0000x reference)
//
#include <hip/hip_runtime.h>
#include <type_traits>

#define NQ 10
#define N_DEPTH 5
#define DIM 1024
#define BATCH 16384
#define IN_DIM 784
#define NGATES 50
#define KALLOC 832    // fp8 row length (13*64); cols >=784 zero
#define NT 13         // K-tiles of 64
#define NSLOT 768     // kept complex amp slots (p0|p1), group-blocked
#define NB 12         // gemm n-blocks (1536 fp8 rows / 128)

typedef float f32x2 __attribute__((ext_vector_type(2)));
typedef float f32x4 __attribute__((ext_vector_type(4)));
typedef unsigned u32x4 __attribute__((ext_vector_type(4)));

// ---------------------------------------------------------------------------
// Compile-time mask tables: CNOTs absorbed into GF(2)-linear index transform.
// ---------------------------------------------------------------------------
struct MaskTab {
  unsigned v[NGATES];
  unsigned p[NGATES];
  unsigned vz0, vz1;
};

constexpr MaskTab make_masks() {
  MaskTab t{};
  unsigned v[NQ], p[NQ];
  for (int i = 0; i < NQ; ++i) { v[i] = 1u << (9 - i); p[i] = 1u << (9 - i); }
  for (int d = 0; d < N_DEPTH; ++d) {
    for (int i = 0; i < NQ; ++i) {
      int c = i, tt = (i + 1) % NQ;
      v[tt] ^= v[c];
      p[c]  ^= p[tt];
    }
    for (int i = 0; i < NQ; ++i) {
      t.v[d * NQ + i] = v[i];
      t.p[d * NQ + i] = p[i];
    }
  }
  t.vz0 = v[0];
  t.vz1 = v[1];
  return t;
}

constexpr MaskTab MT = make_masks();
__constant__ MaskTab d_MT = make_masks();

// Permutation: state m -> slot. Groups of 256 complex slots:
//   A [0,256): p0=1,p1=0   B [256,512): p0=0,p1=1   C [512,768): p0=1,p1=1
// z0 = n2 - 2(SA+SC), z1 = n2 - 2(SB+SC); n2 = |x|^2 exact (unitarity).
struct PermTab { short slot[DIM]; };
constexpr PermTab make_perm() {
  PermTab t{};
  int a = 0, b = 256, c = 512;
  for (int m = 0; m < DIM; ++m) {
    const int p0 = __builtin_popcount((unsigned)m & MT.vz0) & 1;
    const int p1 = __builtin_popcount((unsigned)m & MT.vz1) & 1;
    if (p0 && !p1)      t.slot[m] = (short)a++;
    else if (!p0 && p1) t.slot[m] = (short)b++;
    else if (p0 && p1)  t.slot[m] = (short)c++;
    else                t.slot[m] = -1;
  }
  return t;
}
__constant__ PermTab d_PT = make_perm();

// d = co*o + cp*q (complex), packed (re,im); 4 VOP3P instrs (verified r2-r19).
__device__ __forceinline__ f32x2 ampfma(f32x2 o, f32x2 q, f32x2 co, f32x2 cp) {
  f32x2 d;
  asm("v_pk_mul_f32 %0, %2, %1 op_sel:[0,0] op_sel_hi:[0,1]\n\t"
      "v_pk_fma_f32 %0, %2, %1, %0 op_sel:[1,1,0] op_sel_hi:[1,0,1] neg_lo:[1,0,0]\n\t"
      "v_pk_fma_f32 %0, %3, %4, %0 op_sel:[0,0,0] op_sel_hi:[0,1,1]\n\t"
      "v_pk_fma_f32 %0, %3, %4, %0 op_sel:[1,1,0] op_sel_hi:[1,0,1] neg_lo:[1,0,0]"
      : "=&v"(d)
      : "v"(o), "v"(co), "v"(cp), "v"(q));
  return d;
}

__device__ __forceinline__ float fxor(float x, unsigned m) {
  return __uint_as_float(__float_as_uint(x) ^ m);
}

// pack 4 f32 -> 4 fp8 e4m3 bytes (OCP) in a u32
__device__ __forceinline__ unsigned pk4_fp8(float a, float b, float c, float d) {
  int v = __builtin_amdgcn_cvt_pk_fp8_f32(a, b, 0, false);
  v = __builtin_amdgcn_cvt_pk_fp8_f32(c, d, v, true);
  return (unsigned)v;
}

__device__ __forceinline__ void gll16(const void* g, void* l) {
  __builtin_amdgcn_global_load_lds(
      (const __attribute__((address_space(1))) void*)g,
      (__attribute__((address_space(3))) void*)l, 16, 0, 0);
}

#define XSCALE 32.0f
#define WSCALE 16.0f
#define SINV   (1.0f / 262144.0f)   // 1/(32*16)^2

// ---------------------------------------------------------------------------
// K0+K1 merged. build_w blocks FIRST:
//   blocks [0, 832):     basis columns e_j -> W2T[1536 rows][832 j] fp8,
//                        scatter-written (no transpose pass). Gate loop
//                        processes TWO gates per barrier (XOR-group closure:
//                        post-(g+1) at m needs pre-g at {m, m^p0, m^p1,
//                        m^p0^p1}) -> 25 barriers instead of 50.
//   blocks [832, 2880):  xcvt 8 rows/block: X f32 -> Xf8 (x*32) + xn2 = |x|^2
// ---------------------------------------------------------------------------
__global__ __launch_bounds__(256) void prep(const float* __restrict__ X,
                                            char* __restrict__ Xf8,
                                            float* __restrict__ xn2,
                                            const float* __restrict__ w,
                                            char* __restrict__ W2T) {
  __shared__ f32x4 UL4[NGATES];
  __shared__ f32x2 S0[DIM];
  __shared__ f32x2 S1[DIM];

  const int tid = threadIdx.x;

  if (blockIdx.x >= 832) {
    // ---- xcvt + row-norm: 8 rows/block, 32 lanes/row; 52 chunks of 16 ----
    const int row = (blockIdx.x - 832) * 8 + (tid >> 5);
    const int l32 = tid & 31;
    const float* src = X + (size_t)row * IN_DIM;
    char* dst = Xf8 + (size_t)row * KALLOC;
    float ssq = 0.0f;
    for (int c = l32; c < 52; c += 32) {
      u32x4 out;
      if (c < 49) {                                // 49*16 = 784 exactly
        f32x4 v0 = *(const f32x4*)(src + c * 16);
        f32x4 v1 = *(const f32x4*)(src + c * 16 + 4);
        f32x4 v2 = *(const f32x4*)(src + c * 16 + 8);
        f32x4 v3 = *(const f32x4*)(src + c * 16 + 12);
        ssq += v0.x * v0.x + v0.y * v0.y + v0.z * v0.z + v0.w * v0.w +
               v1.x * v1.x + v1.y * v1.y + v1.z * v1.z + v1.w * v1.w +
               v2.x * v2.x + v2.y * v2.y + v2.z * v2.z + v2.w * v2.w +
               v3.x * v3.x + v3.y * v3.y + v3.z * v3.z + v3.w * v3.w;
        out = u32x4{
          pk4_fp8(v0.x * XSCALE, v0.y * XSCALE, v0.z * XSCALE, v0.w * XSCALE),
          pk4_fp8(v1.x * XSCALE, v1.y * XSCALE, v1.z * XSCALE, v1.w * XSCALE),
          pk4_fp8(v2.x * XSCALE, v2.y * XSCALE, v2.z * XSCALE, v2.w * XSCALE),
          pk4_fp8(v3.x * XSCALE, v3.y * XSCALE, v3.z * XSCALE, v3.w * XSCALE)};
      } else {
        out = u32x4{0, 0, 0, 0};
      }
      *(u32x4*)(dst + c * 16) = out;
    }
#pragma unroll
    for (int off = 1; off < 32; off <<= 1) ssq += __shfl_xor(ssq, off);
    if (l32 == 0) xn2[row] = ssq;
    return;
  }

  // ---- build_w (gate math verified r6-r19; paired-gate schedule new) ----
  if (tid < NGATES) {
    // qml.Rot(phi, theta, omega) = RZ(omega) RY(theta) RZ(phi)
    float phi = w[tid * 3 + 0], th = w[tid * 3 + 1], om = w[tid * 3 + 2];
    float ct = cosf(th * 0.5f), st = sinf(th * 0.5f);
    float aa = (phi + om) * 0.5f, bb = (phi - om) * 0.5f;
    float cA = cosf(aa), sA = sinf(aa), cB = cosf(bb), sB = sinf(bb);
    // u00 = e^{-ia} c ; u01 = -e^{+ib} s  (u11 = conj(u00), u10 = -conj(u01))
    UL4[tid] = f32x4{ ct * cA, -ct * sA, -st * cB, -st * sB };
  }

  const int j = blockIdx.x;                     // 0..831

  if (j >= IN_DIM) {                            // zero pad columns j>=784
#pragma unroll
    for (int k = 0; k < 3; ++k) {
      const int s = tid + k * 256;              // slot 0..767
      W2T[(size_t)(2 * s) * KALLOC + j] = 0;
      W2T[(size_t)(2 * s + 1) * KALLOC + j] = 0;
    }
    return;
  }

#pragma unroll
  for (int k = 0; k < 4; ++k) {
    const int m = tid + k * 256;
    S0[m] = f32x2{(m == j) ? 1.0f : 0.0f, 0.0f};
  }
  __syncthreads();

  // 25 gate-pairs, one barrier each. Pair i: src = buf(i&1), dst = buf(~i&1).
  for (int gp = 0; gp < NGATES / 2; ++gp) {
    const f32x2* src = (gp & 1) ? S1 : S0;
    f32x2* dst = (gp & 1) ? S0 : S1;
    const f32x4 A0 = UL4[2 * gp];
    const f32x4 A1 = UL4[2 * gp + 1];
    const unsigned v0 = d_MT.v[2 * gp],     p0 = d_MT.p[2 * gp];
    const unsigned v1 = d_MT.v[2 * gp + 1], p1 = d_MT.p[2 * gp + 1];
#pragma unroll
    for (int k = 0; k < 4; ++k) {
      const unsigned m = (unsigned)(tid + k * 256);
      // pre-gate values at the 4 closure positions
      f32x2 s00 = src[m];
      f32x2 s01 = src[m ^ p0];
      f32x2 s10 = src[m ^ p1];
      f32x2 s11 = src[m ^ p0 ^ p1];
      // gate g at position m
      const unsigned sgA = (unsigned)(__popc((int)(m & v0)) & 1) << 31;
      f32x2 coA = {A0.x, fxor(A0.y, sgA)};
      f32x2 cpA = {fxor(A0.z, sgA), A0.w};
      f32x2 t0 = ampfma(s00, s01, coA, cpA);
      // gate g at position m^p1
      const unsigned sgB = (unsigned)(__popc((int)((m ^ p1) & v0)) & 1) << 31;
      f32x2 coB = {A0.x, fxor(A0.y, sgB)};
      f32x2 cpB = {fxor(A0.z, sgB), A0.w};
      f32x2 t1 = ampfma(s10, s11, coB, cpB);
      // gate g+1 at position m
      const unsigned sgC = (unsigned)(__popc((int)(m & v1)) & 1) << 31;
      f32x2 coC = {A1.x, fxor(A1.y, sgC)};
      f32x2 cpC = {fxor(A1.z, sgC), A1.w};
      dst[m] = ampfma(t0, t1, coC, cpC);
    }
    __syncthreads();
  }

  const f32x2* fin = S1;   // 25 pairs (odd) -> final state in S1
#pragma unroll
  for (int k = 0; k < 4; ++k) {
    const int m = tid + k * 256;
    const int s = d_PT.slot[m];
    f32x2 a = fin[m];
    if (s >= 0) {
      const unsigned pk = pk4_fp8(a.x * WSCALE, a.y * WSCALE, 0.0f, 0.0f);
      W2T[(size_t)(2 * s) * KALLOC + j] = (char)(pk & 0xffu);
      W2T[(size_t)(2 * s + 1) * KALLOC + j] = (char)((pk >> 8) & 0xffu);
    }
  }
}

// ---------------------------------------------------------------------------
// K3 (r18-exact, best measured 44 us): fp8 gemm, 768 blocks (64mb x 12nb),
// LDS 2 x (A 16KB + B 8KB) = 48KB -> 3 blocks/CU, 768 = 3*256 exact fill.
// 8 waves 2M x 4N, wave tile 128x32, acc[8][2]. BK=64, 13 tiles, one
// barrier/tile, swizzle chunk' = c ^ sw(row), sw(r) = (r&3)^((r>>2)&3).
// ---------------------------------------------------------------------------
__global__ __launch_bounds__(512) void gemm_fused(const char* __restrict__ Xf8,
                                                  const char* __restrict__ W2T,
                                                  float* __restrict__ accb) {
  __shared__ u32x4 lds4[3072];   // 48 KB
  char* lds = (char*)lds4;

  const int tid = threadIdx.x;
  const int orig = blockIdx.x;                    // 768 blocks
  const int bx = (orig & 7) * 96 + (orig >> 3);   // XCD-chunked (768%8==0)
  const int mb = bx / NB, nb = bx % NB;
  const int m0 = mb * 256, n0 = nb * 128;
  const int lane = tid & 63, wv = tid >> 6;
  const int wm = wv >> 2, wn = wv & 3;

  const int rl = lane >> 2;
  const int csrc = (lane & 3) ^ (rl & 3) ^ ((rl >> 2) & 3);

  auto stage = [&](int t) {
    char* Ab = lds + (t & 1) * 24576;
    char* Bb = Ab + 16384;
    const int col = t * 64 + csrc * 16;
#pragma unroll
    for (int i = 0; i < 2; ++i) {                 // A: 2 units/wave (16 total)
      const int g = wv * 2 + i;
      const int row = g * 16 + rl;
      gll16(Xf8 + (size_t)(m0 + row) * KALLOC + col, Ab + g * 1024);
    }
    {                                             // B: 1 unit/wave (8 total)
      const int row = wv * 16 + rl;
      gll16(W2T + (size_t)(n0 + row) * KALLOC + col, Bb + wv * 1024);
    }
  };

  stage(0);
  asm volatile("s_waitcnt vmcnt(0)" ::: "memory");
  __builtin_amdgcn_s_barrier();

  f32x4 acc[8][2];
#pragma unroll
  for (int fm = 0; fm < 8; ++fm)
#pragma unroll
    for (int fn = 0; fn < 2; ++fn) acc[fm][fn] = f32x4{0, 0, 0, 0};

  const int kc = lane >> 4;                       // k-chunk-of-8 within K=32

  for (int t = 0; t < NT; ++t) {
    const char* Ab = lds + (t & 1) * 24576;
    const char* Bb = Ab + 16384;

    long af0[8], bf0[2], af1[8], bf1[2];
    // fragment byte offset within row: kb = kh*4+kc ->
    //   ((kb>>1) ^ sw(row))*16 + (kb&1)*8
#pragma unroll
    for (int f = 0; f < 8; ++f) {
      const int ar = wm * 128 + f * 16 + (lane & 15);
      const int sw = (ar & 3) ^ ((ar >> 2) & 3);
      af0[f] = *(const long*)(Ab + ar * 64 + (((kc >> 1) ^ sw) * 16) + (kc & 1) * 8);
    }
#pragma unroll
    for (int f = 0; f < 2; ++f) {
      const int br = wn * 32 + f * 16 + (lane & 15);
      const int sw = (br & 3) ^ ((br >> 2) & 3);
      bf0[f] = *(const long*)(Bb + br * 64 + (((kc >> 1) ^ sw) * 16) + (kc & 1) * 8);
    }
    if (t < NT - 1) stage(t + 1);                 // -> other buffer (safe)
#pragma unroll
    for (int f = 0; f < 8; ++f) {
      const int ar = wm * 128 + f * 16 + (lane & 15);
      const int sw = (ar & 3) ^ ((ar >> 2) & 3);
      const int kb = 4 + kc;
      af1[f] = *(const long*)(Ab + ar * 64 + (((kb >> 1) ^ sw) * 16) + (kb & 1) * 8);
    }
#pragma unroll
    for (int f = 0; f < 2; ++f) {
      const int br = wn * 32 + f * 16 + (lane & 15);
      const int sw = (br & 3) ^ ((br >> 2) & 3);
      const int kb = 4 + kc;
      bf1[f] = *(const long*)(Bb + br * 64 + (((kb >> 1) ^ sw) * 16) + (kb & 1) * 8);
    }

    __builtin_amdgcn_s_setprio(1);
#pragma unroll
    for (int fm = 0; fm < 8; ++fm)
#pragma unroll
      for (int fn = 0; fn < 2; ++fn)
        acc[fm][fn] = __builtin_amdgcn_mfma_f32_16x16x32_fp8_fp8(
            af0[fm], bf0[fn], acc[fm][fn], 0, 0, 0);
    __builtin_amdgcn_s_setprio(0);

    __builtin_amdgcn_s_setprio(1);
#pragma unroll
    for (int fm = 0; fm < 8; ++fm)
#pragma unroll
      for (int fn = 0; fn < 2; ++fn)
        acc[fm][fn] = __builtin_amdgcn_mfma_f32_16x16x32_fp8_fp8(
            af1[fm], bf1[fn], acc[fm][fn], 0, 0, 0);
    __builtin_amdgcn_s_setprio(0);

    if (t < NT - 1) {
      asm volatile("s_waitcnt vmcnt(0)" ::: "memory");  // next tile landed
      __builtin_amdgcn_sched_barrier(0);
      __builtin_amdgcn_s_barrier();
    }
  }

  // ---- epilogue: per-sample sum |out|^2 for this nb (group-uniform) ----
#pragma unroll
  for (int fm = 0; fm < 8; ++fm) {
    float sn[4] = {0, 0, 0, 0};
#pragma unroll
    for (int fn = 0; fn < 2; ++fn) {
#pragma unroll
      for (int r = 0; r < 4; ++r) {
        const float vv = acc[fm][fn][r];
        sn[r] = fmaf(vv, vv, sn[r]);
      }
    }
#pragma unroll
    for (int off = 1; off < 16; off <<= 1) {
#pragma unroll
      for (int r = 0; r < 4; ++r) sn[r] += __shfl_xor(sn[r], off);
    }
    if ((lane & 15) == 0) {
#pragma unroll
      for (int r = 0; r < 4; ++r) {
        const int m = m0 + wm * 128 + fm * 16 + (lane >> 4) * 4 + r;
        accb[(size_t)nb * BATCH + m] = sn[r];
      }
    }
  }
}

// ---------------------------------------------------------------------------
// K4/K5: per-sample loss + mean reduction. S scaled by 1/(32*16)^2.
// Groups: A = nb 0-3, B = nb 4-7, C = nb 8-11.
// ---------------------------------------------------------------------------
__global__ __launch_bounds__(256) void loss_partial(const float* __restrict__ accb,
                                                    const float* __restrict__ xn2,
                                                    const int* __restrict__ y,
                                                    float* __restrict__ partial) {
  const int s = blockIdx.x * 256 + threadIdx.x;
  float SA = 0.0f, SB = 0.0f, SC = 0.0f;
#pragma unroll
  for (int k = 0; k < 4; ++k) {
    SA += accb[(size_t)(0 + k) * BATCH + s];
    SB += accb[(size_t)(4 + k) * BATCH + s];
    SC += accb[(size_t)(8 + k) * BATCH + s];
  }
  SA *= SINV; SB *= SINV; SC *= SINV;
  const float n2 = xn2[s];
  const float z0 = n2 - 2.0f * (SA + SC);
  const float z1 = n2 - 2.0f * (SB + SC);
  const float inv = 1.0f / n2;
  const float l0 = z0 * inv, l1 = z1 * inv;
  const float mx = fmaxf(l0, l1);
  const float lse = mx + logf(expf(l0 - mx) + expf(l1 - mx));
  float loss = lse - ((y[s] == 0) ? l0 : l1);

  __shared__ float sm[256];
  sm[threadIdx.x] = loss;
  __syncthreads();
  for (int st = 128; st > 0; st >>= 1) {
    if (threadIdx.x < st) sm[threadIdx.x] += sm[threadIdx.x + st];
    __syncthreads();
  }
  if (threadIdx.x == 0) partial[blockIdx.x] = sm[0];
}

__global__ __launch_bounds__(64) void loss_final(const float* __restrict__ partial,
                                                 float* __restrict__ out) {
  float v = partial[threadIdx.x];
#pragma unroll
  for (int off = 1; off < 64; off <<= 1) v += __shfl_xor(v, off);
  if (threadIdx.x == 0) out[0] = v * (1.0f / (float)BATCH);
}

// ---------------------------------------------------------------------------
extern "C" void kernel_launch(void* const* d_in, const int* in_sizes, int n_in,
                              void* d_out, int out_size, void* d_ws, size_t ws_size,
                              hipStream_t stream) {
  const float* x = (const float*)d_in[0];   // [16384, 784] f32
  const float* w = (const float*)d_in[1];   // [5, 10, 3] f32
  const int*   y = (const int*)d_in[2];     // [16384] i32

  char* ws = (char*)d_ws;
  char*     Xf8  = ws;                               // 16384*832 = 13.63 MB
  char*     W2Tu = ws + 13631488;                    // 1536*832 = 1.28 MB
  float*    xn2  = (float*)(ws + 14909440);          // 64 KB
  float*    accb = (float*)(ws + 14975232);          // 12*16384*4 = 768 KB
  float* partial = (float*)(ws + 15761408);          // 64 f32

  prep<<<2880, 256, 0, stream>>>(x, Xf8, xn2, w, W2Tu);
  gemm_fused<<<768, 512, 0, stream>>>(Xf8, W2Tu, accb);
  loss_partial<<<BATCH / 256, 256, 0, stream>>>(accb, xn2, y, partial);
  loss_final<<<1, 64, 0, stream>>>(partial, (float*)d_out);
}

// Round 21
// 80.456 us; speedup vs baseline: 1.0196x; 1.0196x over previous
//
#include <hip/hip_runtime.h>
#include <type_traits>

#define NQ 10
#define N_DEPTH 5
#define DIM 1024
#define BATCH 16384
#define IN_DIM 784
#define NGATES 50
#define KALLOC 832    // fp8 row length (13*64); cols >=784 zero
#define NT 13         // K-tiles of 64
#define NSLOT 768     // kept complex amp slots (p0|p1), group-blocked
#define NB 12         // gemm n-blocks (1536 fp8 rows / 128)

typedef float f32x2 __attribute__((ext_vector_type(2)));
typedef float f32x4 __attribute__((ext_vector_type(4)));
typedef unsigned u32x4 __attribute__((ext_vector_type(4)));

// ---------------------------------------------------------------------------
// Compile-time mask tables: CNOTs absorbed into GF(2)-linear index transform.
// ---------------------------------------------------------------------------
struct MaskTab {
  unsigned v[NGATES];
  unsigned p[NGATES];
  unsigned vz0, vz1;
};

constexpr MaskTab make_masks() {
  MaskTab t{};
  unsigned v[NQ], p[NQ];
  for (int i = 0; i < NQ; ++i) { v[i] = 1u << (9 - i); p[i] = 1u << (9 - i); }
  for (int d = 0; d < N_DEPTH; ++d) {
    for (int i = 0; i < NQ; ++i) {
      int c = i, tt = (i + 1) % NQ;
      v[tt] ^= v[c];
      p[c]  ^= p[tt];
    }
    for (int i = 0; i < NQ; ++i) {
      t.v[d * NQ + i] = v[i];
      t.p[d * NQ + i] = p[i];
    }
  }
  t.vz0 = v[0];
  t.vz1 = v[1];
  return t;
}

constexpr MaskTab MT = make_masks();
__constant__ MaskTab d_MT = make_masks();

// Permutation: state m -> slot. Groups of 256 complex slots:
//   A [0,256): p0=1,p1=0   B [256,512): p0=0,p1=1   C [512,768): p0=1,p1=1
// z0 = n2 - 2(SA+SC), z1 = n2 - 2(SB+SC); n2 = |x|^2 exact (unitarity).
struct PermTab { short slot[DIM]; };
constexpr PermTab make_perm() {
  PermTab t{};
  int a = 0, b = 256, c = 512;
  for (int m = 0; m < DIM; ++m) {
    const int p0 = __builtin_popcount((unsigned)m & MT.vz0) & 1;
    const int p1 = __builtin_popcount((unsigned)m & MT.vz1) & 1;
    if (p0 && !p1)      t.slot[m] = (short)a++;
    else if (!p0 && p1) t.slot[m] = (short)b++;
    else if (p0 && p1)  t.slot[m] = (short)c++;
    else                t.slot[m] = -1;
  }
  return t;
}
__constant__ PermTab d_PT = make_perm();

// d = co*o + cp*q (complex), packed (re,im); 4 VOP3P instrs (verified r2-r20).
__device__ __forceinline__ f32x2 ampfma(f32x2 o, f32x2 q, f32x2 co, f32x2 cp) {
  f32x2 d;
  asm("v_pk_mul_f32 %0, %2, %1 op_sel:[0,0] op_sel_hi:[0,1]\n\t"
      "v_pk_fma_f32 %0, %2, %1, %0 op_sel:[1,1,0] op_sel_hi:[1,0,1] neg_lo:[1,0,0]\n\t"
      "v_pk_fma_f32 %0, %3, %4, %0 op_sel:[0,0,0] op_sel_hi:[0,1,1]\n\t"
      "v_pk_fma_f32 %0, %3, %4, %0 op_sel:[1,1,0] op_sel_hi:[1,0,1] neg_lo:[1,0,0]"
      : "=&v"(d)
      : "v"(o), "v"(co), "v"(cp), "v"(q));
  return d;
}

__device__ __forceinline__ float fxor(float x, unsigned m) {
  return __uint_as_float(__float_as_uint(x) ^ m);
}

// pack 4 f32 -> 4 fp8 e4m3 bytes (OCP) in a u32
__device__ __forceinline__ unsigned pk4_fp8(float a, float b, float c, float d) {
  int v = __builtin_amdgcn_cvt_pk_fp8_f32(a, b, 0, false);
  v = __builtin_amdgcn_cvt_pk_fp8_f32(c, d, v, true);
  return (unsigned)v;
}

__device__ __forceinline__ void gll16(const void* g, void* l) {
  __builtin_amdgcn_global_load_lds(
      (const __attribute__((address_space(1))) void*)g,
      (__attribute__((address_space(3))) void*)l, 16, 0, 0);
}

#define XSCALE 32.0f
#define WSCALE 16.0f
#define SINV   (1.0f / 262144.0f)   // 1/(32*16)^2

// ---------------------------------------------------------------------------
// K0+K1 merged (r17-exact build_w: coalesced u16 W2u writes, no scatter).
//   blocks [0, 832):     basis columns e_j -> W2u[j][768 slots] fp8 (re,im)
//   blocks [832, 2880):  xcvt 8 rows/block: X f32 -> Xf8 (x*32) + xn2 = |x|^2
// ---------------------------------------------------------------------------
__global__ __launch_bounds__(256) void prep(const float* __restrict__ X,
                                            char* __restrict__ Xf8,
                                            float* __restrict__ xn2,
                                            const float* __restrict__ w,
                                            unsigned short* __restrict__ W2u) {
  __shared__ f32x4 UL4[NGATES];
  __shared__ f32x2 S0[DIM];
  __shared__ f32x2 S1[DIM];

  const int tid = threadIdx.x;

  if (blockIdx.x >= 832) {
    // ---- xcvt + row-norm: 8 rows/block, 32 lanes/row; 52 chunks of 16 ----
    const int row = (blockIdx.x - 832) * 8 + (tid >> 5);
    const int l32 = tid & 31;
    const float* src = X + (size_t)row * IN_DIM;
    char* dst = Xf8 + (size_t)row * KALLOC;
    float ssq = 0.0f;
    for (int c = l32; c < 52; c += 32) {
      u32x4 out;
      if (c < 49) {                                // 49*16 = 784 exactly
        f32x4 v0 = *(const f32x4*)(src + c * 16);
        f32x4 v1 = *(const f32x4*)(src + c * 16 + 4);
        f32x4 v2 = *(const f32x4*)(src + c * 16 + 8);
        f32x4 v3 = *(const f32x4*)(src + c * 16 + 12);
        ssq += v0.x * v0.x + v0.y * v0.y + v0.z * v0.z + v0.w * v0.w +
               v1.x * v1.x + v1.y * v1.y + v1.z * v1.z + v1.w * v1.w +
               v2.x * v2.x + v2.y * v2.y + v2.z * v2.z + v2.w * v2.w +
               v3.x * v3.x + v3.y * v3.y + v3.z * v3.z + v3.w * v3.w;
        out = u32x4{
          pk4_fp8(v0.x * XSCALE, v0.y * XSCALE, v0.z * XSCALE, v0.w * XSCALE),
          pk4_fp8(v1.x * XSCALE, v1.y * XSCALE, v1.z * XSCALE, v1.w * XSCALE),
          pk4_fp8(v2.x * XSCALE, v2.y * XSCALE, v2.z * XSCALE, v2.w * XSCALE),
          pk4_fp8(v3.x * XSCALE, v3.y * XSCALE, v3.z * XSCALE, v3.w * XSCALE)};
      } else {
        out = u32x4{0, 0, 0, 0};
      }
      *(u32x4*)(dst + c * 16) = out;
    }
#pragma unroll
    for (int off = 1; off < 32; off <<= 1) ssq += __shfl_xor(ssq, off);
    if (l32 == 0) xn2[row] = ssq;
    return;
  }

  // ---- build_w (r17-exact; gate loop verified r6-r20) ----
  if (tid < NGATES) {
    // qml.Rot(phi, theta, omega) = RZ(omega) RY(theta) RZ(phi)
    float phi = w[tid * 3 + 0], th = w[tid * 3 + 1], om = w[tid * 3 + 2];
    float ct = cosf(th * 0.5f), st = sinf(th * 0.5f);
    float aa = (phi + om) * 0.5f, bb = (phi - om) * 0.5f;
    float cA = cosf(aa), sA = sinf(aa), cB = cosf(bb), sB = sinf(bb);
    // u00 = e^{-ia} c ; u01 = -e^{+ib} s  (u11 = conj(u00), u10 = -conj(u01))
    UL4[tid] = f32x4{ ct * cA, -ct * sA, -st * cB, -st * sB };
  }

  const int j = blockIdx.x;                     // 0..831
  unsigned short* rowp = W2u + (size_t)j * NSLOT;

  if (j >= IN_DIM) {                            // zero pad rows
#pragma unroll
    for (int k = 0; k < 3; ++k) rowp[tid + k * 256] = 0;
    return;
  }

#pragma unroll
  for (int k = 0; k < 4; ++k) {
    const int m = tid + k * 256;
    S0[m] = f32x2{(m == j) ? 1.0f : 0.0f, 0.0f};
  }
  __syncthreads();

  for (int g = 0; g < NGATES; ++g) {
    const f32x2* src = (g & 1) ? S1 : S0;
    f32x2* dst = (g & 1) ? S0 : S1;
    const f32x4 A = UL4[g];
    const unsigned v = d_MT.v[g];
    const unsigned p = d_MT.p[g];
#pragma unroll
    for (int k = 0; k < 4; ++k) {
      const int m = tid + k * 256;
      f32x2 o = src[m];
      f32x2 q = src[m ^ (int)p];
      const unsigned sg = (unsigned)(__popc((int)((unsigned)m & v)) & 1) << 31;
      const f32x2 co = {A.x, fxor(A.y, sg)};
      const f32x2 cp = {fxor(A.z, sg), A.w};
      dst[m] = ampfma(o, q, co, cp);
    }
    __syncthreads();
  }

  const f32x2* fin = S0;   // 50 gates (even) -> final state back in S0
#pragma unroll
  for (int k = 0; k < 4; ++k) {
    const int m = tid + k * 256;
    const int s = d_PT.slot[m];
    f32x2 a = fin[m];
    if (s >= 0)
      rowp[s] = (unsigned short)(pk4_fp8(a.x * WSCALE, a.y * WSCALE,
                                         0.0f, 0.0f) & 0xffffu);
  }
}

// ---------------------------------------------------------------------------
// K2 (r17-exact): transpose W2u [832 j][768 u16 slots] -> W2T [1536 fp8 rows]
// [832 j bytes]. Output row 2*slot+c holds component c (re/im) of slot.
// ---------------------------------------------------------------------------
__global__ __launch_bounds__(256) void transpose_w(const unsigned* __restrict__ W2u32,
                                                   unsigned* __restrict__ W2Tu32) {
  __shared__ unsigned tile[64][33];   // [jr][sc]: 2 slots per u32
  const int j0 = blockIdx.x * 64;     // gridDim.x = 13
  const int s0 = blockIdx.y * 64;     // gridDim.y = 12 (slots)
  const int t = threadIdx.x;
#pragma unroll
  for (int i = 0; i < 8; ++i) {
    const int idx = i * 256 + t;
    const int jr = idx >> 5, sc = idx & 31;
    tile[jr][sc] = W2u32[(size_t)(j0 + jr) * (NSLOT / 2) + (s0 >> 1) + sc];
  }
  __syncthreads();
#pragma unroll
  for (int i = 0; i < 8; ++i) {
    const int idx = i * 256 + t;          // 2048 = 128 rows x 16 u32-cols
    const int rl = idx >> 4, jq = idx & 15;
    const int slot = rl >> 1, c = rl & 1;
    const int sc = slot >> 1, p = slot & 1;
    unsigned out = 0;
#pragma unroll
    for (int q = 0; q < 4; ++q) {
      const unsigned w32 = tile[jq * 4 + q][sc];
      const unsigned h = (w32 >> (16 * p)) & 0xffffu;
      out |= ((h >> (8 * c)) & 0xffu) << (8 * q);
    }
    const int orow = 2 * (s0 + slot) + c;
    W2Tu32[((size_t)orow * KALLOC + j0 + jq * 4) >> 2] = out;
  }
}

// ---------------------------------------------------------------------------
// K3 (r18-exact, best measured 44 us): fp8 gemm, 768 blocks (64mb x 12nb),
// LDS 2 x (A 16KB + B 8KB) = 48KB -> 3 blocks/CU, 768 = 3*256 exact fill.
// 8 waves 2M x 4N, wave tile 128x32, acc[8][2]. BK=64, 13 tiles, one
// barrier/tile, swizzle chunk' = c ^ sw(row), sw(r) = (r&3)^((r>>2)&3).
// ---------------------------------------------------------------------------
__global__ __launch_bounds__(512) void gemm_fused(const char* __restrict__ Xf8,
                                                  const char* __restrict__ W2T,
                                                  float* __restrict__ accb) {
  __shared__ u32x4 lds4[3072];   // 48 KB
  char* lds = (char*)lds4;

  const int tid = threadIdx.x;
  const int orig = blockIdx.x;                    // 768 blocks
  const int bx = (orig & 7) * 96 + (orig >> 3);   // XCD-chunked (768%8==0)
  const int mb = bx / NB, nb = bx % NB;
  const int m0 = mb * 256, n0 = nb * 128;
  const int lane = tid & 63, wv = tid >> 6;
  const int wm = wv >> 2, wn = wv & 3;

  const int rl = lane >> 2;
  const int csrc = (lane & 3) ^ (rl & 3) ^ ((rl >> 2) & 3);

  auto stage = [&](int t) {
    char* Ab = lds + (t & 1) * 24576;
    char* Bb = Ab + 16384;
    const int col = t * 64 + csrc * 16;
#pragma unroll
    for (int i = 0; i < 2; ++i) {                 // A: 2 units/wave (16 total)
      const int g = wv * 2 + i;
      const int row = g * 16 + rl;
      gll16(Xf8 + (size_t)(m0 + row) * KALLOC + col, Ab + g * 1024);
    }
    {                                             // B: 1 unit/wave (8 total)
      const int row = wv * 16 + rl;
      gll16(W2T + (size_t)(n0 + row) * KALLOC + col, Bb + wv * 1024);
    }
  };

  stage(0);
  asm volatile("s_waitcnt vmcnt(0)" ::: "memory");
  __builtin_amdgcn_s_barrier();

  f32x4 acc[8][2];
#pragma unroll
  for (int fm = 0; fm < 8; ++fm)
#pragma unroll
    for (int fn = 0; fn < 2; ++fn) acc[fm][fn] = f32x4{0, 0, 0, 0};

  const int kc = lane >> 4;                       // k-chunk-of-8 within K=32

  for (int t = 0; t < NT; ++t) {
    const char* Ab = lds + (t & 1) * 24576;
    const char* Bb = Ab + 16384;

    long af0[8], bf0[2], af1[8], bf1[2];
    // fragment byte offset within row: kb = kh*4+kc ->
    //   ((kb>>1) ^ sw(row))*16 + (kb&1)*8
#pragma unroll
    for (int f = 0; f < 8; ++f) {
      const int ar = wm * 128 + f * 16 + (lane & 15);
      const int sw = (ar & 3) ^ ((ar >> 2) & 3);
      af0[f] = *(const long*)(Ab + ar * 64 + (((kc >> 1) ^ sw) * 16) + (kc & 1) * 8);
    }
#pragma unroll
    for (int f = 0; f < 2; ++f) {
      const int br = wn * 32 + f * 16 + (lane & 15);
      const int sw = (br & 3) ^ ((br >> 2) & 3);
      bf0[f] = *(const long*)(Bb + br * 64 + (((kc >> 1) ^ sw) * 16) + (kc & 1) * 8);
    }
    if (t < NT - 1) stage(t + 1);                 // -> other buffer (safe)
#pragma unroll
    for (int f = 0; f < 8; ++f) {
      const int ar = wm * 128 + f * 16 + (lane & 15);
      const int sw = (ar & 3) ^ ((ar >> 2) & 3);
      const int kb = 4 + kc;
      af1[f] = *(const long*)(Ab + ar * 64 + (((kb >> 1) ^ sw) * 16) + (kb & 1) * 8);
    }
#pragma unroll
    for (int f = 0; f < 2; ++f) {
      const int br = wn * 32 + f * 16 + (lane & 15);
      const int sw = (br & 3) ^ ((br >> 2) & 3);
      const int kb = 4 + kc;
      bf1[f] = *(const long*)(Bb + br * 64 + (((kb >> 1) ^ sw) * 16) + (kb & 1) * 8);
    }

    __builtin_amdgcn_s_setprio(1);
#pragma unroll
    for (int fm = 0; fm < 8; ++fm)
#pragma unroll
      for (int fn = 0; fn < 2; ++fn)
        acc[fm][fn] = __builtin_amdgcn_mfma_f32_16x16x32_fp8_fp8(
            af0[fm], bf0[fn], acc[fm][fn], 0, 0, 0);
    __builtin_amdgcn_s_setprio(0);

    __builtin_amdgcn_s_setprio(1);
#pragma unroll
    for (int fm = 0; fm < 8; ++fm)
#pragma unroll
      for (int fn = 0; fn < 2; ++fn)
        acc[fm][fn] = __builtin_amdgcn_mfma_f32_16x16x32_fp8_fp8(
            af1[fm], bf1[fn], acc[fm][fn], 0, 0, 0);
    __builtin_amdgcn_s_setprio(0);

    if (t < NT - 1) {
      asm volatile("s_waitcnt vmcnt(0)" ::: "memory");  // next tile landed
      __builtin_amdgcn_sched_barrier(0);
      __builtin_amdgcn_s_barrier();
    }
  }

  // ---- epilogue: per-sample sum |out|^2 for this nb (group-uniform) ----
#pragma unroll
  for (int fm = 0; fm < 8; ++fm) {
    float sn[4] = {0, 0, 0, 0};
#pragma unroll
    for (int fn = 0; fn < 2; ++fn) {
#pragma unroll
      for (int r = 0; r < 4; ++r) {
        const float vv = acc[fm][fn][r];
        sn[r] = fmaf(vv, vv, sn[r]);
      }
    }
#pragma unroll
    for (int off = 1; off < 16; off <<= 1) {
#pragma unroll
      for (int r = 0; r < 4; ++r) sn[r] += __shfl_xor(sn[r], off);
    }
    if ((lane & 15) == 0) {
#pragma unroll
      for (int r = 0; r < 4; ++r) {
        const int m = m0 + wm * 128 + fm * 16 + (lane >> 4) * 4 + r;
        accb[(size_t)nb * BATCH + m] = sn[r];
      }
    }
  }
}

// ---------------------------------------------------------------------------
// K4/K5: per-sample loss + mean reduction. S scaled by 1/(32*16)^2.
// Groups: A = nb 0-3, B = nb 4-7, C = nb 8-11.
// ---------------------------------------------------------------------------
__global__ __launch_bounds__(256) void loss_partial(const float* __restrict__ accb,
                                                    const float* __restrict__ xn2,
                                                    const int* __restrict__ y,
                                                    float* __restrict__ partial) {
  const int s = blockIdx.x * 256 + threadIdx.x;
  float SA = 0.0f, SB = 0.0f, SC = 0.0f;
#pragma unroll
  for (int k = 0; k < 4; ++k) {
    SA += accb[(size_t)(0 + k) * BATCH + s];
    SB += accb[(size_t)(4 + k) * BATCH + s];
    SC += accb[(size_t)(8 + k) * BATCH + s];
  }
  SA *= SINV; SB *= SINV; SC *= SINV;
  const float n2 = xn2[s];
  const float z0 = n2 - 2.0f * (SA + SC);
  const float z1 = n2 - 2.0f * (SB + SC);
  const float inv = 1.0f / n2;
  const float l0 = z0 * inv, l1 = z1 * inv;
  const float mx = fmaxf(l0, l1);
  const float lse = mx + logf(expf(l0 - mx) + expf(l1 - mx));
  float loss = lse - ((y[s] == 0) ? l0 : l1);

  __shared__ float sm[256];
  sm[threadIdx.x] = loss;
  __syncthreads();
  for (int st = 128; st > 0; st >>= 1) {
    if (threadIdx.x < st) sm[threadIdx.x] += sm[threadIdx.x + st];
    __syncthreads();
  }
  if (threadIdx.x == 0) partial[blockIdx.x] = sm[0];
}

__global__ __launch_bounds__(64) void loss_final(const float* __restrict__ partial,
                                                 float* __restrict__ out) {
  float v = partial[threadIdx.x];
#pragma unroll
  for (int off = 1; off < 64; off <<= 1) v += __shfl_xor(v, off);
  if (threadIdx.x == 0) out[0] = v * (1.0f / (float)BATCH);
}

// ---------------------------------------------------------------------------
extern "C" void kernel_launch(void* const* d_in, const int* in_sizes, int n_in,
                              void* d_out, int out_size, void* d_ws, size_t ws_size,
                              hipStream_t stream) {
  const float* x = (const float*)d_in[0];   // [16384, 784] f32
  const float* w = (const float*)d_in[1];   // [5, 10, 3] f32
  const int*   y = (const int*)d_in[2];     // [16384] i32

  char* ws = (char*)d_ws;
  char*     Xf8  = ws;                               // 16384*832 = 13.63 MB
  unsigned short* W2u = (unsigned short*)(ws + 13631488);  // 832*768*2 = 1.28 MB
  char*     W2Tu = ws + 14909440;                    // 1536*832 = 1.28 MB
  float*    xn2  = (float*)(ws + 16187392);          // 64 KB
  float*    accb = (float*)(ws + 16252928);          // 12*16384*4 = 768 KB
  float* partial = (float*)(ws + 17039360);          // 64 f32

  prep<<<2880, 256, 0, stream>>>(x, Xf8, xn2, w, W2u);
  transpose_w<<<dim3(13, 12), 256, 0, stream>>>((const unsigned*)W2u,
                                                (unsigned*)W2Tu);
  gemm_fused<<<768, 512, 0, stream>>>(Xf8, W2Tu, accb);
  loss_partial<<<BATCH / 256, 256, 0, stream>>>(accb, xn2, y, partial);
  loss_final<<<1, 64, 0, stream>>>(partial, (float*)d_out);
}

// Round 22
// 76.913 us; speedup vs baseline: 1.0665x; 1.0461x over previous
//
#include <hip/hip_runtime.h>
#include <type_traits>

#define NQ 10
#define N_DEPTH 5
#define DIM 1024
#define BATCH 16384
#define IN_DIM 784
#define NGATES 50
#define KALLOC 832    // fp8 row length (13*64); cols >=784 zero
#define NT 13         // K-tiles of 64
#define NSLOT 768     // kept complex amp slots (p0|p1), group-blocked
#define NB 12         // gemm n-blocks (1536 fp8 rows / 128)

typedef float f32x2 __attribute__((ext_vector_type(2)));
typedef float f32x4 __attribute__((ext_vector_type(4)));
typedef unsigned u32x4 __attribute__((ext_vector_type(4)));

// ---------------------------------------------------------------------------
// Compile-time mask tables: CNOTs absorbed into GF(2)-linear index transform.
// ---------------------------------------------------------------------------
struct MaskTab {
  unsigned v[NGATES];
  unsigned p[NGATES];
  unsigned vz0, vz1;
};

constexpr MaskTab make_masks() {
  MaskTab t{};
  unsigned v[NQ], p[NQ];
  for (int i = 0; i < NQ; ++i) { v[i] = 1u << (9 - i); p[i] = 1u << (9 - i); }
  for (int d = 0; d < N_DEPTH; ++d) {
    for (int i = 0; i < NQ; ++i) {
      int c = i, tt = (i + 1) % NQ;
      v[tt] ^= v[c];
      p[c]  ^= p[tt];
    }
    for (int i = 0; i < NQ; ++i) {
      t.v[d * NQ + i] = v[i];
      t.p[d * NQ + i] = p[i];
    }
  }
  t.vz0 = v[0];
  t.vz1 = v[1];
  return t;
}

constexpr MaskTab MT = make_masks();

// Permutation: state m -> slot. Groups of 256 complex slots:
//   A [0,256): p0=1,p1=0   B [256,512): p0=0,p1=1   C [512,768): p0=1,p1=1
// z0 = n2 - 2(SA+SC), z1 = n2 - 2(SB+SC); n2 = |x|^2 exact (unitarity).
struct PermTab { short slot[DIM]; };
constexpr PermTab make_perm() {
  PermTab t{};
  int a = 0, b = 256, c = 512;
  for (int m = 0; m < DIM; ++m) {
    const int p0 = __builtin_popcount((unsigned)m & MT.vz0) & 1;
    const int p1 = __builtin_popcount((unsigned)m & MT.vz1) & 1;
    if (p0 && !p1)      t.slot[m] = (short)a++;
    else if (!p0 && p1) t.slot[m] = (short)b++;
    else if (p0 && p1)  t.slot[m] = (short)c++;
    else                t.slot[m] = -1;
  }
  return t;
}
__constant__ PermTab d_PT = make_perm();

// ---------------------------------------------------------------------------
// Bit plan for register-resident build_w: m = waveBits | regBits | laneBits.
// Wave bits chosen (constexpr search) to minimize gates whose p crosses them.
// ---------------------------------------------------------------------------
struct BitPlan { int wpos[2]; int rpos[2]; int lpos[6]; unsigned wmask; };
constexpr BitPlan make_plan() {
  BitPlan bp{};
  int bestc = 1000; unsigned best = 3;
  for (int a = 0; a < NQ; ++a)
    for (int b = a + 1; b < NQ; ++b) {
      unsigned m = (1u << a) | (1u << b);
      int c = 0;
      for (int g = 0; g < NGATES; ++g) if (MT.p[g] & m) ++c;
      if (c < bestc) { bestc = c; best = m; }
    }
  bp.wmask = best;
  int rem[NQ]; int nr = 0, wi = 0;
  for (int b = 0; b < NQ; ++b) {
    if (best & (1u << b)) bp.wpos[wi++] = b;
    else rem[nr++] = b;
  }
  for (int i = 0; i < 6; ++i) bp.lpos[i] = rem[i];
  bp.rpos[0] = rem[6]; bp.rpos[1] = rem[7];
  return bp;
}
constexpr BitPlan BP = make_plan();

constexpr unsigned gath_l(unsigned p) {
  unsigned r = 0;
  for (int i = 0; i < 6; ++i) if (p & (1u << BP.lpos[i])) r |= 1u << i;
  return r;
}
constexpr unsigned gath_r(unsigned p) {
  unsigned r = 0;
  for (int i = 0; i < 2; ++i) if (p & (1u << BP.rpos[i])) r |= 1u << i;
  return r;
}
constexpr unsigned scat_r(unsigned x) {
  return ((x & 1u) << BP.rpos[0]) | (((x >> 1) & 1u) << BP.rpos[1]);
}
constexpr int ncross_before(int g) {
  int c = 0;
  for (int i = 0; i < g; ++i) if (MT.p[i] & BP.wmask) ++c;
  return c;
}

template <int I, int N, typename F>
__device__ __forceinline__ void static_for(F&& f) {
  if constexpr (I < N) {
    f(std::integral_constant<int, I>{});
    static_for<I + 1, N>(static_cast<F&&>(f));
  }
}

// ---------------------------------------------------------------------------
// Cross-lane XOR exchange (VALU DPP/permlane; DS fallback) — verified r3/r4.
// ---------------------------------------------------------------------------
constexpr int xcost(unsigned m) {
  constexpr int t[16] = {0,1,1,1,2,2,2,1,1,2,2,2,2,2,2,1};
  return t[m & 15u] + (((m >> 4) & 1u) ? 3 : 0) + (((m >> 5) & 1u) ? 3 : 0);
}

template <int CTRL>
__device__ __forceinline__ float dppf(float x) {
  int xi = (int)__float_as_uint(x);
  return __uint_as_float(
      (unsigned)__builtin_amdgcn_update_dpp(xi, xi, CTRL, 0xF, 0xF, false));
}

__device__ __forceinline__ float plswap16(float x) {
  float a = x, b = x;
  asm("s_nop 1\n\t"
      "v_permlane16_swap_b32 %0, %1" : "+v"(a), "+v"(b));
  return (a + b) - x;
}
__device__ __forceinline__ float plswap32(float x) {
  float a = x, b = x;
  asm("s_nop 1\n\t"
      "v_permlane32_swap_b32 %0, %1" : "+v"(a), "+v"(b));
  return (a + b) - x;
}

template <unsigned M>
__device__ __forceinline__ float xlane_f(float x) {
  float r = x;
  constexpr unsigned m4 = M & 15u;
  if constexpr (m4 == 1u)  r = dppf<0x0B1>(r);
  else if constexpr (m4 == 2u)  r = dppf<0x04E>(r);
  else if constexpr (m4 == 3u)  r = dppf<0x01B>(r);
  else if constexpr (m4 == 4u)  { r = dppf<0x141>(r); r = dppf<0x01B>(r); }
  else if constexpr (m4 == 5u)  { r = dppf<0x141>(r); r = dppf<0x04E>(r); }
  else if constexpr (m4 == 6u)  { r = dppf<0x141>(r); r = dppf<0x0B1>(r); }
  else if constexpr (m4 == 7u)  r = dppf<0x141>(r);
  else if constexpr (m4 == 8u)  r = dppf<0x128>(r);
  else if constexpr (m4 == 9u)  { r = dppf<0x128>(r); r = dppf<0x0B1>(r); }
  else if constexpr (m4 == 10u) { r = dppf<0x128>(r); r = dppf<0x04E>(r); }
  else if constexpr (m4 == 11u) { r = dppf<0x128>(r); r = dppf<0x01B>(r); }
  else if constexpr (m4 == 12u) { r = dppf<0x140>(r); r = dppf<0x01B>(r); }
  else if constexpr (m4 == 13u) { r = dppf<0x140>(r); r = dppf<0x04E>(r); }
  else if constexpr (m4 == 14u) { r = dppf<0x140>(r); r = dppf<0x0B1>(r); }
  else if constexpr (m4 == 15u) r = dppf<0x140>(r);
  if constexpr ((M & 16u) != 0u) r = plswap16(r);
  if constexpr ((M & 32u) != 0u) r = plswap32(r);
  return r;
}

template <unsigned M>
__device__ __forceinline__ f32x2 xchg(f32x2 v) {
  if constexpr (M == 0u) {
    return v;
  } else if constexpr (xcost(M) >= 5) {
    f32x2 r;
    r.x = __shfl_xor(v.x, (int)M);
    r.y = __shfl_xor(v.y, (int)M);
    return r;
  } else {
    f32x2 r;
    r.x = xlane_f<M>(v.x);
    r.y = xlane_f<M>(v.y);
    return r;
  }
}

// d = co*o + cp*q (complex), packed (re,im); 4 VOP3P instrs (verified r2-r21).
__device__ __forceinline__ f32x2 ampfma(f32x2 o, f32x2 q, f32x2 co, f32x2 cp) {
  f32x2 d;
  asm("v_pk_mul_f32 %0, %2, %1 op_sel:[0,0] op_sel_hi:[0,1]\n\t"
      "v_pk_fma_f32 %0, %2, %1, %0 op_sel:[1,1,0] op_sel_hi:[1,0,1] neg_lo:[1,0,0]\n\t"
      "v_pk_fma_f32 %0, %3, %4, %0 op_sel:[0,0,0] op_sel_hi:[0,1,1]\n\t"
      "v_pk_fma_f32 %0, %3, %4, %0 op_sel:[1,1,0] op_sel_hi:[1,0,1] neg_lo:[1,0,0]"
      : "=&v"(d)
      : "v"(o), "v"(co), "v"(cp), "v"(q));
  return d;
}

__device__ __forceinline__ float fxor(float x, unsigned m) {
  return __uint_as_float(__float_as_uint(x) ^ m);
}

// pack 4 f32 -> 4 fp8 e4m3 bytes (OCP) in a u32
__device__ __forceinline__ unsigned pk4_fp8(float a, float b, float c, float d) {
  int v = __builtin_amdgcn_cvt_pk_fp8_f32(a, b, 0, false);
  v = __builtin_amdgcn_cvt_pk_fp8_f32(c, d, v, true);
  return (unsigned)v;
}

__device__ __forceinline__ void gll16(const void* g, void* l) {
  __builtin_amdgcn_global_load_lds(
      (const __attribute__((address_space(1))) void*)g,
      (__attribute__((address_space(3))) void*)l, 16, 0, 0);
}

#define XSCALE 32.0f
#define WSCALE 16.0f
#define SINV   (1.0f / 262144.0f)   // 1/(32*16)^2

// ---------------------------------------------------------------------------
// K0+K1 merged. build_w (register-resident, wave-bit planned) blocks FIRST:
//   blocks [0, 832):     basis columns e_j -> W2u[j][768 slots] fp8 (re,im)
//   blocks [832, 2880):  xcvt 8 rows/block: X f32 -> Xf8 (x*32) + xn2 = |x|^2
// ---------------------------------------------------------------------------
__global__ __launch_bounds__(256) void prep(const float* __restrict__ X,
                                            char* __restrict__ Xf8,
                                            float* __restrict__ xn2,
                                            const float* __restrict__ w,
                                            unsigned short* __restrict__ W2u) {
  __shared__ f32x4 UL4[NGATES];
  __shared__ f32x2 S0[DIM];
  __shared__ f32x2 S1[DIM];

  const int tid = threadIdx.x;

  if (blockIdx.x >= 832) {
    // ---- xcvt + row-norm: 8 rows/block, 32 lanes/row; 52 chunks of 16 ----
    const int row = (blockIdx.x - 832) * 8 + (tid >> 5);
    const int l32 = tid & 31;
    const float* src = X + (size_t)row * IN_DIM;
    char* dst = Xf8 + (size_t)row * KALLOC;
    float ssq = 0.0f;
    for (int c = l32; c < 52; c += 32) {
      u32x4 out;
      if (c < 49) {                                // 49*16 = 784 exactly
        f32x4 v0 = *(const f32x4*)(src + c * 16);
        f32x4 v1 = *(const f32x4*)(src + c * 16 + 4);
        f32x4 v2 = *(const f32x4*)(src + c * 16 + 8);
        f32x4 v3 = *(const f32x4*)(src + c * 16 + 12);
        ssq += v0.x * v0.x + v0.y * v0.y + v0.z * v0.z + v0.w * v0.w +
               v1.x * v1.x + v1.y * v1.y + v1.z * v1.z + v1.w * v1.w +
               v2.x * v2.x + v2.y * v2.y + v2.z * v2.z + v2.w * v2.w +
               v3.x * v3.x + v3.y * v3.y + v3.z * v3.z + v3.w * v3.w;
        out = u32x4{
          pk4_fp8(v0.x * XSCALE, v0.y * XSCALE, v0.z * XSCALE, v0.w * XSCALE),
          pk4_fp8(v1.x * XSCALE, v1.y * XSCALE, v1.z * XSCALE, v1.w * XSCALE),
          pk4_fp8(v2.x * XSCALE, v2.y * XSCALE, v2.z * XSCALE, v2.w * XSCALE),
          pk4_fp8(v3.x * XSCALE, v3.y * XSCALE, v3.z * XSCALE, v3.w * XSCALE)};
      } else {
        out = u32x4{0, 0, 0, 0};
      }
      *(u32x4*)(dst + c * 16) = out;
    }
#pragma unroll
    for (int off = 1; off < 32; off <<= 1) ssq += __shfl_xor(ssq, off);
    if (l32 == 0) xn2[row] = ssq;
    return;
  }

  // ---- build_w v4: state in registers, m = waveBits|regBits|laneBits ----
  if (tid < NGATES) {
    // qml.Rot(phi, theta, omega) = RZ(omega) RY(theta) RZ(phi)
    float phi = w[tid * 3 + 0], th = w[tid * 3 + 1], om = w[tid * 3 + 2];
    float ct = cosf(th * 0.5f), st = sinf(th * 0.5f);
    float aa = (phi + om) * 0.5f, bb = (phi - om) * 0.5f;
    float cA = cosf(aa), sA = sinf(aa), cB = cosf(bb), sB = sinf(bb);
    // u00 = e^{-ia} c ; u01 = -e^{+ib} s  (u11 = conj(u00), u10 = -conj(u01))
    UL4[tid] = f32x4{ ct * cA, -ct * sA, -st * cB, -st * sB };
  }

  const int j = blockIdx.x;                     // 0..831
  unsigned short* rowp = W2u + (size_t)j * NSLOT;

  if (j >= IN_DIM) {                            // zero pad rows
#pragma unroll
    for (int k = 0; k < 3; ++k) rowp[tid + k * 256] = 0;
    return;
  }

  const int wv = tid >> 6, lane = tid & 63;
  unsigned mbase = ((unsigned)(wv & 1) << BP.wpos[0]) |
                   ((unsigned)(wv >> 1) << BP.wpos[1]);
#pragma unroll
  for (int i = 0; i < 6; ++i)
    mbase |= (((unsigned)lane >> i) & 1u) << BP.lpos[i];

  f32x2 a[4];
  static_for<0, 4>([&](auto R_) {
    constexpr int r = decltype(R_)::value;
    constexpr unsigned rs = scat_r((unsigned)r);
    a[r] = f32x2{((mbase | rs) == (unsigned)j) ? 1.0f : 0.0f, 0.0f};
  });
  __syncthreads();   // UL4 staged

  static_for<0, NGATES>([&](auto G_) {
    constexpr int G = decltype(G_)::value;
    constexpr unsigned p = MT.p[G];
    constexpr unsigned v = MT.v[G];
    constexpr unsigned pw = p & BP.wmask;
    const f32x4 A = UL4[G];

    if constexpr (pw == 0u) {
      constexpr unsigned lx = gath_l(p);
      constexpr unsigned rx = gath_r(p);
      if constexpr (rx == 0u) {
        static_for<0, 4>([&](auto R_) {
          constexpr int r = decltype(R_)::value;
          constexpr unsigned rs = scat_r((unsigned)r);
          f32x2 o = a[r];
          f32x2 q = xchg<lx>(o);
          const unsigned sg =
              (unsigned)(__popc((int)((mbase | rs) & v)) & 1) << 31;
          const f32x2 co = {A.x, fxor(A.y, sg)};
          const f32x2 cp = {fxor(A.z, sg), A.w};
          a[r] = ampfma(o, q, co, cp);
        });
      } else {
        static_for<0, 4>([&](auto R_) {
          constexpr int r = decltype(R_)::value;
          constexpr int r2 = r ^ (int)rx;
          if constexpr (r < r2) {
            constexpr unsigned rs0 = scat_r((unsigned)r);
            constexpr unsigned rs1 = scat_r((unsigned)r2);
            f32x2 o0 = a[r], o1 = a[r2];
            f32x2 q0 = xchg<lx>(o1);
            f32x2 q1 = xchg<lx>(o0);
            const unsigned sg0 =
                (unsigned)(__popc((int)((mbase | rs0) & v)) & 1) << 31;
            const unsigned sg1 =
                (unsigned)(__popc((int)((mbase | rs1) & v)) & 1) << 31;
            const f32x2 co0 = {A.x, fxor(A.y, sg0)};
            const f32x2 cp0 = {fxor(A.z, sg0), A.w};
            const f32x2 co1 = {A.x, fxor(A.y, sg1)};
            const f32x2 cp1 = {fxor(A.z, sg1), A.w};
            a[r]  = ampfma(o0, q0, co0, cp0);
            a[r2] = ampfma(o1, q1, co1, cp1);
          }
        });
      }
    } else {
      // wave-crossing gate: ping-pong LDS round, one barrier
      constexpr int cidx = ncross_before(G);
      f32x2* S = (cidx & 1) ? S1 : S0;
      static_for<0, 4>([&](auto R_) {
        constexpr int r = decltype(R_)::value;
        constexpr unsigned rs = scat_r((unsigned)r);
        S[mbase | rs] = a[r];
      });
      __syncthreads();
      static_for<0, 4>([&](auto R_) {
        constexpr int r = decltype(R_)::value;
        constexpr unsigned rs = scat_r((unsigned)r);
        const unsigned m = mbase | rs;
        f32x2 o = a[r];
        f32x2 q = S[m ^ p];
        const unsigned sg = (unsigned)(__popc((int)(m & v)) & 1) << 31;
        const f32x2 co = {A.x, fxor(A.y, sg)};
        const f32x2 cp = {fxor(A.z, sg), A.w};
        a[r] = ampfma(o, q, co, cp);
      });
    }
  });

  // store fp8 (re,im) u16 per kept slot
  static_for<0, 4>([&](auto R_) {
    constexpr int r = decltype(R_)::value;
    constexpr unsigned rs = scat_r((unsigned)r);
    const unsigned m = mbase | rs;
    const int s = d_PT.slot[m];
    if (s >= 0)
      rowp[s] = (unsigned short)(pk4_fp8(a[r].x * WSCALE, a[r].y * WSCALE,
                                         0.0f, 0.0f) & 0xffffu);
  });
}

// ---------------------------------------------------------------------------
// K2 (r17-exact): transpose W2u [832 j][768 u16 slots] -> W2T [1536 fp8 rows]
// [832 j bytes]. Output row 2*slot+c holds component c (re/im) of slot.
// ---------------------------------------------------------------------------
__global__ __launch_bounds__(256) void transpose_w(const unsigned* __restrict__ W2u32,
                                                   unsigned* __restrict__ W2Tu32) {
  __shared__ unsigned tile[64][33];   // [jr][sc]: 2 slots per u32
  const int j0 = blockIdx.x * 64;     // gridDim.x = 13
  const int s0 = blockIdx.y * 64;     // gridDim.y = 12 (slots)
  const int t = threadIdx.x;
#pragma unroll
  for (int i = 0; i < 8; ++i) {
    const int idx = i * 256 + t;
    const int jr = idx >> 5, sc = idx & 31;
    tile[jr][sc] = W2u32[(size_t)(j0 + jr) * (NSLOT / 2) + (s0 >> 1) + sc];
  }
  __syncthreads();
#pragma unroll
  for (int i = 0; i < 8; ++i) {
    const int idx = i * 256 + t;          // 2048 = 128 rows x 16 u32-cols
    const int rl = idx >> 4, jq = idx & 15;
    const int slot = rl >> 1, c = rl & 1;
    const int sc = slot >> 1, p = slot & 1;
    unsigned out = 0;
#pragma unroll
    for (int q = 0; q < 4; ++q) {
      const unsigned w32 = tile[jq * 4 + q][sc];
      const unsigned h = (w32 >> (16 * p)) & 0xffffu;
      out |= ((h >> (8 * c)) & 0xffu) << (8 * q);
    }
    const int orow = 2 * (s0 + slot) + c;
    W2Tu32[((size_t)orow * KALLOC + j0 + jq * 4) >> 2] = out;
  }
}

// ---------------------------------------------------------------------------
// K3 (r18-exact, best measured 44 us): fp8 gemm, 768 blocks (64mb x 12nb),
// LDS 2 x (A 16KB + B 8KB) = 48KB -> 3 blocks/CU, 768 = 3*256 exact fill.
// 8 waves 2M x 4N, wave tile 128x32, acc[8][2]. BK=64, 13 tiles, one
// barrier/tile, swizzle chunk' = c ^ sw(row), sw(r) = (r&3)^((r>>2)&3).
// ---------------------------------------------------------------------------
__global__ __launch_bounds__(512) void gemm_fused(const char* __restrict__ Xf8,
                                                  const char* __restrict__ W2T,
                                                  float* __restrict__ accb) {
  __shared__ u32x4 lds4[3072];   // 48 KB
  char* lds = (char*)lds4;

  const int tid = threadIdx.x;
  const int orig = blockIdx.x;                    // 768 blocks
  const int bx = (orig & 7) * 96 + (orig >> 3);   // XCD-chunked (768%8==0)
  const int mb = bx / NB, nb = bx % NB;
  const int m0 = mb * 256, n0 = nb * 128;
  const int lane = tid & 63, wv = tid >> 6;
  const int wm = wv >> 2, wn = wv & 3;

  const int rl = lane >> 2;
  const int csrc = (lane & 3) ^ (rl & 3) ^ ((rl >> 2) & 3);

  auto stage = [&](int t) {
    char* Ab = lds + (t & 1) * 24576;
    char* Bb = Ab + 16384;
    const int col = t * 64 + csrc * 16;
#pragma unroll
    for (int i = 0; i < 2; ++i) {                 // A: 2 units/wave (16 total)
      const int g = wv * 2 + i;
      const int row = g * 16 + rl;
      gll16(Xf8 + (size_t)(m0 + row) * KALLOC + col, Ab + g * 1024);
    }
    {                                             // B: 1 unit/wave (8 total)
      const int row = wv * 16 + rl;
      gll16(W2T + (size_t)(n0 + row) * KALLOC + col, Bb + wv * 1024);
    }
  };

  stage(0);
  asm volatile("s_waitcnt vmcnt(0)" ::: "memory");
  __builtin_amdgcn_s_barrier();

  f32x4 acc[8][2];
#pragma unroll
  for (int fm = 0; fm < 8; ++fm)
#pragma unroll
    for (int fn = 0; fn < 2; ++fn) acc[fm][fn] = f32x4{0, 0, 0, 0};

  const int kc = lane >> 4;                       // k-chunk-of-8 within K=32

  for (int t = 0; t < NT; ++t) {
    const char* Ab = lds + (t & 1) * 24576;
    const char* Bb = Ab + 16384;

    long af0[8], bf0[2], af1[8], bf1[2];
    // fragment byte offset within row: kb = kh*4+kc ->
    //   ((kb>>1) ^ sw(row))*16 + (kb&1)*8
#pragma unroll
    for (int f = 0; f < 8; ++f) {
      const int ar = wm * 128 + f * 16 + (lane & 15);
      const int sw = (ar & 3) ^ ((ar >> 2) & 3);
      af0[f] = *(const long*)(Ab + ar * 64 + (((kc >> 1) ^ sw) * 16) + (kc & 1) * 8);
    }
#pragma unroll
    for (int f = 0; f < 2; ++f) {
      const int br = wn * 32 + f * 16 + (lane & 15);
      const int sw = (br & 3) ^ ((br >> 2) & 3);
      bf0[f] = *(const long*)(Bb + br * 64 + (((kc >> 1) ^ sw) * 16) + (kc & 1) * 8);
    }
    if (t < NT - 1) stage(t + 1);                 // -> other buffer (safe)
#pragma unroll
    for (int f = 0; f < 8; ++f) {
      const int ar = wm * 128 + f * 16 + (lane & 15);
      const int sw = (ar & 3) ^ ((ar >> 2) & 3);
      const int kb = 4 + kc;
      af1[f] = *(const long*)(Ab + ar * 64 + (((kb >> 1) ^ sw) * 16) + (kb & 1) * 8);
    }
#pragma unroll
    for (int f = 0; f < 2; ++f) {
      const int br = wn * 32 + f * 16 + (lane & 15);
      const int sw = (br & 3) ^ ((br >> 2) & 3);
      const int kb = 4 + kc;
      bf1[f] = *(const long*)(Bb + br * 64 + (((kb >> 1) ^ sw) * 16) + (kb & 1) * 8);
    }

    __builtin_amdgcn_s_setprio(1);
#pragma unroll
    for (int fm = 0; fm < 8; ++fm)
#pragma unroll
      for (int fn = 0; fn < 2; ++fn)
        acc[fm][fn] = __builtin_amdgcn_mfma_f32_16x16x32_fp8_fp8(
            af0[fm], bf0[fn], acc[fm][fn], 0, 0, 0);
    __builtin_amdgcn_s_setprio(0);

    __builtin_amdgcn_s_setprio(1);
#pragma unroll
    for (int fm = 0; fm < 8; ++fm)
#pragma unroll
      for (int fn = 0; fn < 2; ++fn)
        acc[fm][fn] = __builtin_amdgcn_mfma_f32_16x16x32_fp8_fp8(
            af1[fm], bf1[fn], acc[fm][fn], 0, 0, 0);
    __builtin_amdgcn_s_setprio(0);

    if (t < NT - 1) {
      asm volatile("s_waitcnt vmcnt(0)" ::: "memory");  // next tile landed
      __builtin_amdgcn_sched_barrier(0);
      __builtin_amdgcn_s_barrier();
    }
  }

  // ---- epilogue: per-sample sum |out|^2 for this nb (group-uniform) ----
#pragma unroll
  for (int fm = 0; fm < 8; ++fm) {
    float sn[4] = {0, 0, 0, 0};
#pragma unroll
    for (int fn = 0; fn < 2; ++fn) {
#pragma unroll
      for (int r = 0; r < 4; ++r) {
        const float vv = acc[fm][fn][r];
        sn[r] = fmaf(vv, vv, sn[r]);
      }
    }
#pragma unroll
    for (int off = 1; off < 16; off <<= 1) {
#pragma unroll
      for (int r = 0; r < 4; ++r) sn[r] += __shfl_xor(sn[r], off);
    }
    if ((lane & 15) == 0) {
#pragma unroll
      for (int r = 0; r < 4; ++r) {
        const int m = m0 + wm * 128 + fm * 16 + (lane >> 4) * 4 + r;
        accb[(size_t)nb * BATCH + m] = sn[r];
      }
    }
  }
}

// ---------------------------------------------------------------------------
// K4/K5: per-sample loss + mean reduction. S scaled by 1/(32*16)^2.
// Groups: A = nb 0-3, B = nb 4-7, C = nb 8-11.
// ---------------------------------------------------------------------------
__global__ __launch_bounds__(256) void loss_partial(const float* __restrict__ accb,
                                                    const float* __restrict__ xn2,
                                                    const int* __restrict__ y,
                                                    float* __restrict__ partial) {
  const int s = blockIdx.x * 256 + threadIdx.x;
  float SA = 0.0f, SB = 0.0f, SC = 0.0f;
#pragma unroll
  for (int k = 0; k < 4; ++k) {
    SA += accb[(size_t)(0 + k) * BATCH + s];
    SB += accb[(size_t)(4 + k) * BATCH + s];
    SC += accb[(size_t)(8 + k) * BATCH + s];
  }
  SA *= SINV; SB *= SINV; SC *= SINV;
  const float n2 = xn2[s];
  const float z0 = n2 - 2.0f * (SA + SC);
  const float z1 = n2 - 2.0f * (SB + SC);
  const float inv = 1.0f / n2;
  const float l0 = z0 * inv, l1 = z1 * inv;
  const float mx = fmaxf(l0, l1);
  const float lse = mx + logf(expf(l0 - mx) + expf(l1 - mx));
  float loss = lse - ((y[s] == 0) ? l0 : l1);

  __shared__ float sm[256];
  sm[threadIdx.x] = loss;
  __syncthreads();
  for (int st = 128; st > 0; st >>= 1) {
    if (threadIdx.x < st) sm[threadIdx.x] += sm[threadIdx.x + st];
    __syncthreads();
  }
  if (threadIdx.x == 0) partial[blockIdx.x] = sm[0];
}

__global__ __launch_bounds__(64) void loss_final(const float* __restrict__ partial,
                                                 float* __restrict__ out) {
  float v = partial[threadIdx.x];
#pragma unroll
  for (int off = 1; off < 64; off <<= 1) v += __shfl_xor(v, off);
  if (threadIdx.x == 0) out[0] = v * (1.0f / (float)BATCH);
}

// ---------------------------------------------------------------------------
extern "C" void kernel_launch(void* const* d_in, const int* in_sizes, int n_in,
                              void* d_out, int out_size, void* d_ws, size_t ws_size,
                              hipStream_t stream) {
  const float* x = (const float*)d_in[0];   // [16384, 784] f32
  const float* w = (const float*)d_in[1];   // [5, 10, 3] f32
  const int*   y = (const int*)d_in[2];     // [16384] i32

  char* ws = (char*)d_ws;
  char*     Xf8  = ws;                               // 16384*832 = 13.63 MB
  unsigned short* W2u = (unsigned short*)(ws + 13631488);  // 832*768*2 = 1.28 MB
  char*     W2Tu = ws + 14909440;                    // 1536*832 = 1.28 MB
  float*    xn2  = (float*)(ws + 16187392);          // 64 KB
  float*    accb = (float*)(ws + 16252928);          // 12*16384*4 = 768 KB
  float* partial = (float*)(ws + 17039360);          // 64 f32

  prep<<<2880, 256, 0, stream>>>(x, Xf8, xn2, w, W2u);
  transpose_w<<<dim3(13, 12), 256, 0, stream>>>((const unsigned*)W2u,
                                                (unsigned*)W2Tu);
  gemm_fused<<<768, 512, 0, stream>>>(Xf8, W2Tu, accb);
  loss_partial<<<BATCH / 256, 256, 0, stream>>>(accb, xn2, y, partial);
  loss_final<<<1, 64, 0, stream>>>(partial, (float*)d_out);
}